// Round 13
// baseline (114.581 us; speedup 1.0000x reference)
//
#include <hip/hip_runtime.h>
#include <math.h>

// Problem constants (fixed by the reference setup)
#define B_ 32
#define N_ 2048
#define D_ 64
#define R_ 32
#define T_ 31
#define O_ 12
#define HID_ 128
#define IN_DIM_ 63      // T_ + R_
#define NCH_ 8          // n-chunks (256 rows each): 256 blocks = 1 full wave-generation

// Workspace layout (float offsets)
#define OFF_QSP   0
#define OFF_UPART (OFF_QSP + N_*R_)              // 65536
#define OFF_CTX   (OFF_UPART + B_*NCH_*R_*D_)    // + 524288
#define OFF_PBF   (OFF_CTX + B_*R_)              // bf16 area (ushort*): N*R
#define OFF_SUT   (OFF_PBF + N_*R_/2)            // bf16 area (ushort*): B*O*D*R
// end ~ 1.0M floats ~ 4 MB (< ws)

typedef __attribute__((ext_vector_type(4))) float f32x4;
typedef __attribute__((ext_vector_type(8))) short short8;

__device__ __forceinline__ float softplus_f(float x) {
    return fmaxf(x, 0.0f) + log1pf(expf(-fabsf(x)));
}
__device__ __forceinline__ float gelu_f(float x) {
    return 0.5f * x * (1.0f + erff(x * 0.70710678118654752440f));
}
// float -> bf16 bits, round-to-nearest-even
__device__ __forceinline__ unsigned short f2bf(float f) {
    unsigned int u = __float_as_uint(f);
    u = (u + 0x7FFFu + ((u >> 16) & 1u)) >> 16;
    return (unsigned short)u;
}

// Kernel 1: Qsp = softplus(Q_raw) fp32 (s_load source for k_upart).
__global__ __launch_bounds__(256) void k_softplus(const float* __restrict__ Qr,
                                                  float* __restrict__ ws) {
    int i = blockIdx.x * blockDim.x + threadIdx.x;
    if (i < N_ * R_) ws[OFF_QSP + i] = softplus_f(Qr[i]);
}

// Kernel 2: partial U. grid = B_*NCH_ = 256 blocks, 512 threads (8 waves) ->
// 2048 waves = exactly one full GPU generation; 256-iteration inner loops.
// b==0 blocks emit Pbf for their 256-row chunk (elementwise, coalesced).
__global__ __launch_bounds__(512) void k_upart(const float* __restrict__ H,
                                               const float* __restrict__ Pr,
                                               float* __restrict__ ws) {
    const float* __restrict__ Qsp = ws + OFF_QSP;
    float* __restrict__ Upart = ws + OFF_UPART;
    int b = blockIdx.x / NCH_;
    int c = blockIdx.x % NCH_;
    int tid = threadIdx.x;
    const int n0 = c * (N_ / NCH_);   // 256 rows per chunk

    if (b == 0) {
        unsigned short* Pbf = (unsigned short*)(ws + OFF_PBF);
        #pragma unroll
        for (int i = tid; i < (N_ / NCH_) * R_; i += 512)
            Pbf[(size_t)n0 * R_ + i] = f2bf(softplus_f(Pr[(size_t)n0 * R_ + i]));
    }

    int d = tid & 63;
    int rb = __builtin_amdgcn_readfirstlane(tid >> 6);  // 0..7, wave-uniform
    const int r0 = rb * 4;
    float acc0 = 0.f, acc1 = 0.f, acc2 = 0.f, acc3 = 0.f;
    const float* __restrict__ Hb = H + ((size_t)b * N_ + n0) * D_ + d;
    #pragma unroll 2
    for (int i = 0; i < N_ / NCH_; ++i) {
        float h = Hb[(size_t)i * D_];
        const float* q = Qsp + (size_t)(n0 + i) * R_ + r0;  // uniform -> s_load_dwordx4
        acc0 = fmaf(h, q[0], acc0);
        acc1 = fmaf(h, q[1], acc1);
        acc2 = fmaf(h, q[2], acc2);
        acc3 = fmaf(h, q[3], acc3);
    }
    float* up = Upart + ((size_t)(b * NCH_ + c) * R_ + r0) * D_ + d;
    up[0 * D_] = acc0;
    up[1 * D_] = acc1;
    up[2 * D_] = acc2;
    up[3 * D_] = acc3;
}

// Kernel 3 (k_tail): fused Upart-reduce + ctx + MLP + SUT. grid = B_ = 32, 256 thr.
// U lives only in LDS (the global U round-trip is gone).
__global__ __launch_bounds__(256) void k_tail(const float* __restrict__ ts_out,
                                              const float* __restrict__ W1,
                                              const float* __restrict__ b1,
                                              const float* __restrict__ W2,
                                              const float* __restrict__ b2,
                                              const float* __restrict__ alpha,
                                              float* __restrict__ ws) {
    __shared__ float Ul[R_][D_];        // 8 KB
    __shared__ float ctxl[R_];
    __shared__ float tsl[O_ * T_];
    __shared__ float hsh[O_][HID_];     // 6 KB
    __shared__ float ssh[O_][R_];
    int b = blockIdx.x;
    int tid = threadIdx.x;
    const float* __restrict__ Upart = ws + OFF_UPART;

    // Phase 1: reduce 8 chunks; thread owns (r = tid>>3, d8 = (tid&7)*8)
    {
        int r = tid >> 3;
        int d0 = (tid & 7) * 8;
        f32x4 u0 = {0.f,0.f,0.f,0.f}, u1 = {0.f,0.f,0.f,0.f};
        #pragma unroll
        for (int c = 0; c < NCH_; ++c) {
            const float* p = Upart + ((size_t)(b * NCH_ + c) * R_ + r) * D_ + d0;
            u0 += *(const f32x4*)(p);
            u1 += *(const f32x4*)(p + 4);
        }
        *(f32x4*)(&Ul[r][d0])     = u0;
        *(f32x4*)(&Ul[r][d0 + 4]) = u1;
        float sq = u0[0]*u0[0]+u0[1]*u0[1]+u0[2]*u0[2]+u0[3]*u0[3]
                 + u1[0]*u1[0]+u1[1]*u1[1]+u1[2]*u1[2]+u1[3]*u1[3];
        #pragma unroll
        for (int off = 4; off; off >>= 1) sq += __shfl_xor(sq, off, 8);
        if ((tid & 7) == 0) ctxl[r] = sqrtf(sq * (1.0f / D_) + 1e-6f);
    }
    for (int i = tid; i < O_ * T_; i += 256)
        tsl[i] = ts_out[(size_t)b * O_ * T_ + i];
    __syncthreads();

    // Phase 2: MLP — 2 groups of 128 threads; group g does o = g, g+2, ..., g+10
    int g = tid >> 7;       // 0..1
    int lt = tid & 127;     // hidden neuron
    #pragma unroll
    for (int oo = 0; oo < 6; ++oo) {
        int o = g + oo * 2;
        float acc = b1[lt];
        for (int k = 0; k < T_; ++k) acc = fmaf(tsl[o * T_ + k], W1[k * HID_ + lt], acc);
        for (int k = 0; k < R_; ++k) acc = fmaf(ctxl[k], W1[(T_ + k) * HID_ + lt], acc);
        hsh[o][lt] = gelu_f(acc);
    }
    __syncthreads();
    if (tid < O_ * R_ - 128) { /* nothing: placeholder keeps structure simple */ }
    // s = softplus(h@W2 + b2): 384 outputs, threads 0..255 do 1-2 each
    for (int idx = tid; idx < O_ * R_; idx += 256) {
        int o = idx >> 5, r = idx & 31;
        float a2 = b2[r];
        #pragma unroll 8
        for (int j = 0; j < HID_; ++j) a2 = fmaf(hsh[o][j], W2[j * R_ + r], a2);
        ssh[o][r] = softplus_f(a2);
    }
    __syncthreads();

    // Phase 3: SUT[b,o][d][r] = bf16(a * ssh[o][r] * Ul[r][d]), r fastest (coalesced)
    float a = fminf(fmaxf(alpha[0], 0.0f), 1.0f);
    unsigned short* SUT = (unsigned short*)(ws + OFF_SUT) + (size_t)b * O_ * D_ * R_;
    for (int idx = tid; idx < O_ * D_ * R_; idx += 256) {
        int r = idx & 31, d = (idx >> 5) & 63, o = idx >> 11;
        SUT[idx] = f2bf(a * ssh[o][r] * Ul[r][d]);
    }
}

// Kernel 4 (k_main v3): 2-deep SUT pipeline, H/P hoisted, og fastest grid dim
// (og-pair shares the H tile on one XCD).
//   D[d][n] = sum_r SUT[b,o][d][r] * P[n][r];  out[b,o,n,d] = oma*H + D
// Wave-local LDS transpose -> 1KB-contiguous full-line stores, no barriers.
// grid (2, N/64, B), block 256 (4 waves).
__global__ __launch_bounds__(256) void k_main(const float* __restrict__ H,
                                              const float* __restrict__ alpha,
                                              const float* __restrict__ ws,
                                              float* __restrict__ out) {
    __shared__ float tile[64 * 64];   // 16 KB, wave-sliced rows
    const int og = blockIdx.x;            // 0/1: o in [og*6, og*6+6)
    const int b = blockIdx.z;
    const int nblk = blockIdx.y * 64;
    const int tid = threadIdx.x;
    const int w = tid >> 6;
    const int lane = tid & 63;
    const int l16 = lane & 15;
    const int lhi = lane >> 4;
    const int rl = w * 16 + l16;
    const float a = fminf(fmaxf(alpha[0], 0.0f), 1.0f);
    const float oma = 1.0f - a;

    const unsigned short* Pbf = (const unsigned short*)(ws + OFF_PBF);
    const unsigned short* SUT0 = (const unsigned short*)(ws + OFF_SUT)
                               + (size_t)(b * O_ + og * 6) * D_ * R_;

    // Hoist ALL front loads: H (4x f32x4), P (1x short8), SUT o=0,1 (8x short8)
    const float* __restrict__ Hrow = H + ((size_t)b * N_ + nblk + rl) * D_;
    f32x4 hv[4];
    #pragma unroll
    for (int db = 0; db < 4; ++db)
        hv[db] = *(const f32x4*)(Hrow + db * 16 + lhi * 4);
    short8 pfrag = *(const short8*)(Pbf + (size_t)(nblk + rl) * R_ + lhi * 8);
    short8 sf[3][4];
    #pragma unroll
    for (int db = 0; db < 4; ++db) {
        sf[0][db] = *(const short8*)(SUT0 + (size_t)(db * 16 + l16) * R_ + lhi * 8);
        sf[1][db] = *(const short8*)(SUT0 + (size_t)(D_ * R_ + (db * 16 + l16) * R_) + lhi * 8);
    }
    f32x4 homa[4];
    #pragma unroll
    for (int db = 0; db < 4; ++db) homa[db] = oma * hv[db];

    char* tb = (char*)tile;
    float* __restrict__ oblk = out + ((size_t)(b * O_ + og * 6) * N_ + nblk) * D_;

    #pragma unroll
    for (int oi = 0; oi < 6; ++oi) {
        const int cur = oi % 3;
        // 1. issue o+2's SUT loads (2-deep: never waits on L2/L3 latency)
        if (oi < 4) {
            const int nx2 = (oi + 2) % 3;
            const unsigned short* Sn = SUT0 + (size_t)(oi + 2) * D_ * R_;
            #pragma unroll
            for (int db = 0; db < 4; ++db)
                sf[nx2][db] = *(const short8*)(Sn + (size_t)(db * 16 + l16) * R_ + lhi * 8);
        }
        // 2. MFMA + swizzled ds_write (wave-private rows)
        #pragma unroll
        for (int db = 0; db < 4; ++db) {
            f32x4 v = homa[db] + __builtin_amdgcn_mfma_f32_16x16x32_bf16(
                sf[cur][db], pfrag, (f32x4){0.f, 0.f, 0.f, 0.f}, 0, 0, 0);
            int c = (db * 64 + lhi * 16) ^ ((rl & 7) << 4);
            *(f32x4*)(tb + rl * 256 + c) = v;
        }
        // 3. wave-local linear read-back + full-line stores
        char* op = (char*)(oblk + (size_t)oi * N_ * D_);
        #pragma unroll
        for (int i = 0; i < 4; ++i) {
            int gg = w * 4096 + i * 1024 + lane * 16;
            int rr = gg >> 8;
            int cc = (gg & 255) ^ ((rr & 7) << 4);
            f32x4 v = *(const f32x4*)(tb + rr * 256 + cc);
            *(f32x4*)(op + gg) = v;
        }
    }
}

extern "C" void kernel_launch(void* const* d_in, const int* in_sizes, int n_in,
                              void* d_out, int out_size, void* d_ws, size_t ws_size,
                              hipStream_t stream) {
    const float* H      = (const float*)d_in[0];
    const float* ts_out = (const float*)d_in[1];
    // d_in[2] is O (int scalar) — shapes are compile-time constants here
    const float* P_raw  = (const float*)d_in[3];
    const float* Q_raw  = (const float*)d_in[4];
    const float* W1     = (const float*)d_in[5];
    const float* b1     = (const float*)d_in[6];
    const float* W2     = (const float*)d_in[7];
    const float* b2     = (const float*)d_in[8];
    const float* alpha  = (const float*)d_in[9];
    float* out = (float*)d_out;
    float* ws  = (float*)d_ws;

    // 1. softplus(Q) -> Qsp
    k_softplus<<<dim3((N_ * R_ + 255) / 256), dim3(256), 0, stream>>>(Q_raw, ws);
    // 2. partial U (256 blocks, one full generation; +Pbf from b==0 blocks)
    k_upart<<<dim3(B_ * NCH_), dim3(512), 0, stream>>>(H, P_raw, ws);
    // 3. fused reduce + ctx + MLP + SUT
    k_tail<<<dim3(B_), dim3(256), 0, stream>>>(ts_out, W1, b1, W2, b2, alpha, ws);
    // 4. main fused output (2-deep pipeline, og-fastest grid)
    k_main<<<dim3(2, N_ / 64, B_), dim3(256), 0, stream>>>(H, alpha, ws, out);
}

// Round 14
// 73.561 us; speedup vs baseline: 1.5576x; 1.5576x over previous
//
#include <hip/hip_runtime.h>
#include <math.h>

// Problem constants (fixed by the reference setup)
#define B_ 32
#define N_ 2048
#define D_ 64
#define R_ 32
#define T_ 31
#define O_ 12
#define HID_ 128
#define IN_DIM_ 63      // T_ + R_
#define NCH_ 32         // n-chunks for partial-U reduction (1024 blocks -> 8 waves/SIMD)

// Workspace layout (float offsets)
#define OFF_QSP   0
#define OFF_UPART (OFF_QSP + N_*R_)              // 65536
#define OFF_U     (OFF_UPART + B_*NCH_*R_*D_)    // 2162688
#define OFF_CTX   (OFF_U + B_*R_*D_)             // 2228224
#define OFF_PBF   (OFF_CTX + B_*R_)              // 2229248 (bf16 area, ushort*)
#define OFF_SUT   (OFF_PBF + N_*R_/2)            // 2262016 (bf16 area, ushort*)
// end ~ 2.65M floats ~ 10.6 MB (< ws)

typedef __attribute__((ext_vector_type(4))) float f32x4;
typedef __attribute__((ext_vector_type(8))) short short8;

__device__ __forceinline__ float softplus_f(float x) {
    return fmaxf(x, 0.0f) + log1pf(expf(-fabsf(x)));
}
__device__ __forceinline__ float gelu_f(float x) {
    return 0.5f * x * (1.0f + erff(x * 0.70710678118654752440f));
}
// float -> bf16 bits, round-to-nearest-even
__device__ __forceinline__ unsigned short f2bf(float f) {
    unsigned int u = __float_as_uint(f);
    u = (u + 0x7FFFu + ((u >> 16) & 1u)) >> 16;
    return (unsigned short)u;
}

// Kernel 1: Qsp = softplus(Q_raw) fp32 (s_load source for k_upart).
__global__ __launch_bounds__(256) void k_softplus(const float* __restrict__ Qr,
                                                  float* __restrict__ ws) {
    int i = blockIdx.x * blockDim.x + threadIdx.x;
    if (i < N_ * R_) ws[OFF_QSP + i] = softplus_f(Qr[i]);
}

// Kernel 2a: partial U over n-chunks. grid = B_*NCH_ = 1024 blocks, 512 threads
// (8 waves/SIMD — R13 lesson: 256 blocks = 2 waves/SIMD is latency-starved).
// b==0 blocks also emit Pbf = bf16(softplus(P_raw)) for their 64-row chunk.
__global__ __launch_bounds__(512) void k_upart(const float* __restrict__ H,
                                               const float* __restrict__ Pr,
                                               float* __restrict__ ws) {
    const float* __restrict__ Qsp = ws + OFF_QSP;
    float* __restrict__ Upart = ws + OFF_UPART;
    int b = blockIdx.x / NCH_;
    int c = blockIdx.x % NCH_;
    int tid = threadIdx.x;
    const int n0 = c * (N_ / NCH_);   // 64 rows per chunk

    if (b == 0) {
        unsigned short* Pbf = (unsigned short*)(ws + OFF_PBF);
        #pragma unroll
        for (int i = tid; i < 64 * R_; i += 512)
            Pbf[(size_t)n0 * R_ + i] = f2bf(softplus_f(Pr[(size_t)n0 * R_ + i]));
    }

    int d = tid & 63;
    int rb = __builtin_amdgcn_readfirstlane(tid >> 6);  // 0..7, wave-uniform
    const int r0 = rb * 4;
    float acc0 = 0.f, acc1 = 0.f, acc2 = 0.f, acc3 = 0.f;
    const float* __restrict__ Hb = H + ((size_t)b * N_ + n0) * D_ + d;
    #pragma unroll 2
    for (int i = 0; i < 64; ++i) {
        float h = Hb[(size_t)i * D_];
        const float* q = Qsp + (size_t)(n0 + i) * R_ + r0;  // uniform -> s_load_dwordx4
        acc0 = fmaf(h, q[0], acc0);
        acc1 = fmaf(h, q[1], acc1);
        acc2 = fmaf(h, q[2], acc2);
        acc3 = fmaf(h, q[3], acc3);
    }
    float* up = Upart + ((size_t)(b * NCH_ + c) * R_ + r0) * D_ + d;
    up[0 * D_] = acc0;
    up[1 * D_] = acc1;
    up[2 * D_] = acc2;
    up[3 * D_] = acc3;
}

// Kernel 2b: reduce partials -> U, ctx = sqrt(mean_d U^2 + eps).
// grid (B_, 8) = 256 blocks, 256 threads (r = by*4 + wave).
__global__ __launch_bounds__(256) void k_ured(float* __restrict__ ws) {
    const float* __restrict__ Upart = ws + OFF_UPART;
    float* __restrict__ U = ws + OFF_U;
    float* __restrict__ ctx = ws + OFF_CTX;
    int b = blockIdx.x;
    int r = blockIdx.y * 4 + (threadIdx.x >> 6);
    int d = threadIdx.x & 63;
    float u = 0.f;
    #pragma unroll 8
    for (int c = 0; c < NCH_; ++c)
        u += Upart[((size_t)(b * NCH_ + c) * R_ + r) * D_ + d];
    U[((size_t)b * R_ + r) * D_ + d] = u;
    float sq = u * u;
    #pragma unroll
    for (int off = 32; off; off >>= 1) sq += __shfl_xor(sq, off, 64);
    if (d == 0) ctx[b * R_ + r] = sqrtf(sq * (1.0f / D_) + 1e-6f);
}

// Kernel 3: MLP -> s, then SUT[b,o][d][r] = bf16(a * s[r] * U[b,r,d])
__global__ __launch_bounds__(128) void k_mlp(const float* __restrict__ ts_out,
                                             const float* __restrict__ W1,
                                             const float* __restrict__ b1,
                                             const float* __restrict__ W2,
                                             const float* __restrict__ b2,
                                             const float* __restrict__ alpha,
                                             float* __restrict__ ws) {
    __shared__ float feat[IN_DIM_];
    __shared__ float hsh[HID_];
    __shared__ float ssh[R_];
    int bo = blockIdx.x;
    int b = bo / O_;
    int tid = threadIdx.x;
    const float* __restrict__ ctx = ws + OFF_CTX;
    if (tid < T_) feat[tid] = ts_out[(size_t)bo * T_ + tid];
    else if (tid < IN_DIM_) feat[tid] = ctx[b * R_ + (tid - T_)];
    __syncthreads();
    float acc = b1[tid];
    #pragma unroll 9
    for (int k = 0; k < IN_DIM_; ++k) acc = fmaf(feat[k], W1[k * HID_ + tid], acc);
    hsh[tid] = gelu_f(acc);
    __syncthreads();
    if (tid < R_) {
        float a2 = b2[tid];
        #pragma unroll 8
        for (int j = 0; j < HID_; ++j) a2 = fmaf(hsh[j], W2[j * R_ + tid], a2);
        ssh[tid] = softplus_f(a2);
    }
    __syncthreads();
    float a = fminf(fmaxf(alpha[0], 0.0f), 1.0f);
    const float* __restrict__ U = ws + OFF_U;
    unsigned short* SUT = (unsigned short*)(ws + OFF_SUT) + (size_t)bo * D_ * R_;
    #pragma unroll
    for (int idx = tid; idx < D_ * R_; idx += 128) {
        int d = idx >> 5, r = idx & 31;
        SUT[idx] = f2bf(a * ssh[r] * U[((size_t)b * R_ + r) * D_ + d]);
    }
}

// Kernel 4 (k_main, R12 structure + XCD-locality swizzle):
//   D[d][n] = sum_r SUT[b,o][d][r] * P[n][r];  out[b,o,n,d] = oma*H + D
// 1-D grid 2048, decode chosen so XCD k (= linear id % 8, round-robin dispatch)
// owns b in {4k..4k+3}: its read set (H 2MB + SUT 192KB + P 128KB ~ 2.3MB)
// fits the XCD's 4MB L2 -> repeat reads are L2 hits, not L3/HBM (cold-start
// stalls were the single-pass vs REP-steady gap: 57 vs 29 us, R11 data).
//   vid: xcd = vid&7; slot = vid>>3; nb = slot&31; og = (slot>>5)&1; b = xcd*4 + (slot>>6)
// SUT loads for o+1 issued BEFORE o's stores (in-order vmcnt retirement).
// Wave-local LDS transpose -> 1KB-contiguous full-line stores, no barriers.
__global__ __launch_bounds__(256) void k_main(const float* __restrict__ H,
                                              const float* __restrict__ alpha,
                                              const float* __restrict__ ws,
                                              float* __restrict__ out) {
    __shared__ float tile[64 * 64];   // 16 KB, wave-sliced rows
    const int vid = blockIdx.x;
    const int b   = (vid & 7) * 4 + (vid >> 9);        // slot>>6 = vid>>9
    const int og  = (vid >> 8) & 1;                     // (slot>>5)&1
    const int nblk = ((vid >> 3) & 31) * 64;            // slot&31
    const int tid = threadIdx.x;
    const int w = tid >> 6;
    const int lane = tid & 63;
    const int l16 = lane & 15;
    const int lhi = lane >> 4;
    const int rl = w * 16 + l16;
    const float a = fminf(fmaxf(alpha[0], 0.0f), 1.0f);
    const float oma = 1.0f - a;

    const unsigned short* Pbf = (const unsigned short*)(ws + OFF_PBF);
    const unsigned short* SUT0 = (const unsigned short*)(ws + OFF_SUT)
                               + (size_t)(b * O_ + og * 6) * D_ * R_;

    short8 pfrag = *(const short8*)(Pbf + (size_t)(nblk + rl) * R_ + lhi * 8);

    const float* __restrict__ Hrow = H + ((size_t)b * N_ + nblk + rl) * D_;
    f32x4 homa[4];
    #pragma unroll
    for (int db = 0; db < 4; ++db)
        homa[db] = oma * *(const f32x4*)(Hrow + db * 16 + lhi * 4);

    char* tb = (char*)tile;
    float* __restrict__ oblk = out + ((size_t)(b * O_ + og * 6) * N_ + nblk) * D_;

    short8 sf[2][4];
    #pragma unroll
    for (int db = 0; db < 4; ++db)
        sf[0][db] = *(const short8*)(SUT0 + (size_t)(db * 16 + l16) * R_ + lhi * 8);
    #pragma unroll
    for (int oi = 0; oi < 6; ++oi) {
        const int cur = oi & 1, nxt = cur ^ 1;
        // 1. issue NEXT o's SUT loads first (before this o's stores)
        if (oi < 5) {
            const unsigned short* Sn = SUT0 + (size_t)(oi + 1) * D_ * R_;
            #pragma unroll
            for (int db = 0; db < 4; ++db)
                sf[nxt][db] = *(const short8*)(Sn + (size_t)(db * 16 + l16) * R_ + lhi * 8);
        }
        // 2. MFMA + swizzled ds_write (wave-private rows)
        #pragma unroll
        for (int db = 0; db < 4; ++db) {
            f32x4 v = homa[db] + __builtin_amdgcn_mfma_f32_16x16x32_bf16(
                sf[cur][db], pfrag, (f32x4){0.f, 0.f, 0.f, 0.f}, 0, 0, 0);
            int c = (db * 64 + lhi * 16) ^ ((rl & 7) << 4);
            *(f32x4*)(tb + rl * 256 + c) = v;
        }
        // 3. wave-local linear read-back + full-line stores
        char* op = (char*)(oblk + (size_t)oi * N_ * D_);
        #pragma unroll
        for (int i = 0; i < 4; ++i) {
            int g = w * 4096 + i * 1024 + lane * 16;
            int rr = g >> 8;
            int cc = (g & 255) ^ ((rr & 7) << 4);
            f32x4 v = *(const f32x4*)(tb + rr * 256 + cc);
            *(f32x4*)(op + g) = v;
        }
    }
}

extern "C" void kernel_launch(void* const* d_in, const int* in_sizes, int n_in,
                              void* d_out, int out_size, void* d_ws, size_t ws_size,
                              hipStream_t stream) {
    const float* H      = (const float*)d_in[0];
    const float* ts_out = (const float*)d_in[1];
    // d_in[2] is O (int scalar) — shapes are compile-time constants here
    const float* P_raw  = (const float*)d_in[3];
    const float* Q_raw  = (const float*)d_in[4];
    const float* W1     = (const float*)d_in[5];
    const float* b1     = (const float*)d_in[6];
    const float* W2     = (const float*)d_in[7];
    const float* b2     = (const float*)d_in[8];
    const float* alpha  = (const float*)d_in[9];
    float* out = (float*)d_out;
    float* ws  = (float*)d_ws;

    // 1. softplus(Q) -> Qsp
    k_softplus<<<dim3((N_ * R_ + 255) / 256), dim3(256), 0, stream>>>(Q_raw, ws);
    // 2a. partial U (1024 blocks, 8 waves/SIMD; +Pbf from b==0 blocks)
    k_upart<<<dim3(B_ * NCH_), dim3(512), 0, stream>>>(H, P_raw, ws);
    // 2b. reduce U + ctx (256 blocks)
    k_ured<<<dim3(B_, 8), dim3(256), 0, stream>>>(ws);
    // 3. MLP -> s -> SUT (bf16, [d][r])
    k_mlp<<<dim3(B_ * O_), dim3(128), 0, stream>>>(ts_out, W1, b1, W2, b2, alpha, ws);
    // 4. main fused output (XCD-locality swizzled 1-D grid)
    k_main<<<dim3(2048), dim3(256), 0, stream>>>(H, alpha, ws, out);
}

// Round 15
// 73.488 us; speedup vs baseline: 1.5592x; 1.0010x over previous
//
#include <hip/hip_runtime.h>
#include <math.h>

// Problem constants (fixed by the reference setup)
#define B_ 32
#define N_ 2048
#define D_ 64
#define R_ 32
#define T_ 31
#define O_ 12
#define HID_ 128
#define IN_DIM_ 63      // T_ + R_
#define NCH_ 32         // n-chunks for partial-U reduction (1024 blocks -> 8 waves/SIMD)

// Workspace layout (float offsets)
#define OFF_QSP   0
#define OFF_UPART (OFF_QSP + N_*R_)              // 65536
#define OFF_U     (OFF_UPART + B_*NCH_*R_*D_)    // 2162688
#define OFF_CTX   (OFF_U + B_*R_*D_)             // 2228224
#define OFF_PBF   (OFF_CTX + B_*R_)              // 2229248 (bf16 area, ushort*)
#define OFF_SUT   (OFF_PBF + N_*R_/2)            // 2262016 (bf16 area, ushort*)
// end ~ 2.65M floats ~ 10.6 MB (< ws)

typedef __attribute__((ext_vector_type(4))) float f32x4;
typedef __attribute__((ext_vector_type(8))) short short8;

__device__ __forceinline__ float softplus_f(float x) {
    return fmaxf(x, 0.0f) + log1pf(expf(-fabsf(x)));
}
__device__ __forceinline__ float gelu_f(float x) {
    return 0.5f * x * (1.0f + erff(x * 0.70710678118654752440f));
}
// float -> bf16 bits, round-to-nearest-even
__device__ __forceinline__ unsigned short f2bf(float f) {
    unsigned int u = __float_as_uint(f);
    u = (u + 0x7FFFu + ((u >> 16) & 1u)) >> 16;
    return (unsigned short)u;
}

// Kernel 1: Qsp = softplus(Q_raw) fp32 (s_load source for k_upart).
__global__ __launch_bounds__(256) void k_softplus(const float* __restrict__ Qr,
                                                  float* __restrict__ ws) {
    int i = blockIdx.x * blockDim.x + threadIdx.x;
    if (i < N_ * R_) ws[OFF_QSP + i] = softplus_f(Qr[i]);
}

// Kernel 2a: partial U over n-chunks. grid = B_*NCH_ = 1024 blocks, 512 threads
// (8 waves/SIMD — R13 lesson: 256 blocks = 2 waves/SIMD is latency-starved).
// b==0 blocks also emit Pbf = bf16(softplus(P_raw)) for their 64-row chunk.
__global__ __launch_bounds__(512) void k_upart(const float* __restrict__ H,
                                               const float* __restrict__ Pr,
                                               float* __restrict__ ws) {
    const float* __restrict__ Qsp = ws + OFF_QSP;
    float* __restrict__ Upart = ws + OFF_UPART;
    int b = blockIdx.x / NCH_;
    int c = blockIdx.x % NCH_;
    int tid = threadIdx.x;
    const int n0 = c * (N_ / NCH_);   // 64 rows per chunk

    if (b == 0) {
        unsigned short* Pbf = (unsigned short*)(ws + OFF_PBF);
        #pragma unroll
        for (int i = tid; i < 64 * R_; i += 512)
            Pbf[(size_t)n0 * R_ + i] = f2bf(softplus_f(Pr[(size_t)n0 * R_ + i]));
    }

    int d = tid & 63;
    int rb = __builtin_amdgcn_readfirstlane(tid >> 6);  // 0..7, wave-uniform
    const int r0 = rb * 4;
    float acc0 = 0.f, acc1 = 0.f, acc2 = 0.f, acc3 = 0.f;
    const float* __restrict__ Hb = H + ((size_t)b * N_ + n0) * D_ + d;
    #pragma unroll 2
    for (int i = 0; i < 64; ++i) {
        float h = Hb[(size_t)i * D_];
        const float* q = Qsp + (size_t)(n0 + i) * R_ + r0;  // uniform -> s_load_dwordx4
        acc0 = fmaf(h, q[0], acc0);
        acc1 = fmaf(h, q[1], acc1);
        acc2 = fmaf(h, q[2], acc2);
        acc3 = fmaf(h, q[3], acc3);
    }
    float* up = Upart + ((size_t)(b * NCH_ + c) * R_ + r0) * D_ + d;
    up[0 * D_] = acc0;
    up[1 * D_] = acc1;
    up[2 * D_] = acc2;
    up[3 * D_] = acc3;
}

// Kernel 2b: reduce partials -> U, ctx = sqrt(mean_d U^2 + eps).
// grid (B_, 8) = 256 blocks, 256 threads (r = by*4 + wave).
__global__ __launch_bounds__(256) void k_ured(float* __restrict__ ws) {
    const float* __restrict__ Upart = ws + OFF_UPART;
    float* __restrict__ U = ws + OFF_U;
    float* __restrict__ ctx = ws + OFF_CTX;
    int b = blockIdx.x;
    int r = blockIdx.y * 4 + (threadIdx.x >> 6);
    int d = threadIdx.x & 63;
    float u = 0.f;
    #pragma unroll 8
    for (int c = 0; c < NCH_; ++c)
        u += Upart[((size_t)(b * NCH_ + c) * R_ + r) * D_ + d];
    U[((size_t)b * R_ + r) * D_ + d] = u;
    float sq = u * u;
    #pragma unroll
    for (int off = 32; off; off >>= 1) sq += __shfl_xor(sq, off, 64);
    if (d == 0) ctx[b * R_ + r] = sqrtf(sq * (1.0f / D_) + 1e-6f);
}

// Kernel 3: MLP -> s, then SUT[b,o][d][r] = bf16(a * s[r] * U[b,r,d])
__global__ __launch_bounds__(128) void k_mlp(const float* __restrict__ ts_out,
                                             const float* __restrict__ W1,
                                             const float* __restrict__ b1,
                                             const float* __restrict__ W2,
                                             const float* __restrict__ b2,
                                             const float* __restrict__ alpha,
                                             float* __restrict__ ws) {
    __shared__ float feat[IN_DIM_];
    __shared__ float hsh[HID_];
    __shared__ float ssh[R_];
    int bo = blockIdx.x;
    int b = bo / O_;
    int tid = threadIdx.x;
    const float* __restrict__ ctx = ws + OFF_CTX;
    if (tid < T_) feat[tid] = ts_out[(size_t)bo * T_ + tid];
    else if (tid < IN_DIM_) feat[tid] = ctx[b * R_ + (tid - T_)];
    __syncthreads();
    float acc = b1[tid];
    #pragma unroll 9
    for (int k = 0; k < IN_DIM_; ++k) acc = fmaf(feat[k], W1[k * HID_ + tid], acc);
    hsh[tid] = gelu_f(acc);
    __syncthreads();
    if (tid < R_) {
        float a2 = b2[tid];
        #pragma unroll 8
        for (int j = 0; j < HID_; ++j) a2 = fmaf(hsh[j], W2[j * R_ + tid], a2);
        ssh[tid] = softplus_f(a2);
    }
    __syncthreads();
    float a = fminf(fmaxf(alpha[0], 0.0f), 1.0f);
    const float* __restrict__ U = ws + OFF_U;
    unsigned short* SUT = (unsigned short*)(ws + OFF_SUT) + (size_t)bo * D_ * R_;
    #pragma unroll
    for (int idx = tid; idx < D_ * R_; idx += 128) {
        int d = idx >> 5, r = idx & 31;
        SUT[idx] = f2bf(a * ssh[r] * U[((size_t)b * R_ + r) * D_ + d]);
    }
}

// Kernel 4 (k_main = R14 structure + NON-TEMPORAL full-line stores):
//   D[d][n] = sum_r SUT[b,o][d][r] * P[n][r];  out[b,o,n,d] = oma*H + D
// Single change this round: the final stores use __builtin_nontemporal_store.
// Rationale: single-pass k_main (57us) vs REP-steady (34.8us, R11) differs by
// cold-L2 allocate/evict churn on 201MB of output lines through a 32MB L2.
// Stores here are 1KB-contiguous per wave-instr (full 128B lines), so nt
// bypasses L2 tag allocation cleanly (R7's nt test was on 64B segments +
// confounded — invalid). XCD-locality decode kept from R14 (neutral, harmless).
__global__ __launch_bounds__(256) void k_main(const float* __restrict__ H,
                                              const float* __restrict__ alpha,
                                              const float* __restrict__ ws,
                                              float* __restrict__ out) {
    __shared__ float tile[64 * 64];   // 16 KB, wave-sliced rows
    const int vid = blockIdx.x;
    const int b   = (vid & 7) * 4 + (vid >> 9);
    const int og  = (vid >> 8) & 1;
    const int nblk = ((vid >> 3) & 31) * 64;
    const int tid = threadIdx.x;
    const int w = tid >> 6;
    const int lane = tid & 63;
    const int l16 = lane & 15;
    const int lhi = lane >> 4;
    const int rl = w * 16 + l16;
    const float a = fminf(fmaxf(alpha[0], 0.0f), 1.0f);
    const float oma = 1.0f - a;

    const unsigned short* Pbf = (const unsigned short*)(ws + OFF_PBF);
    const unsigned short* SUT0 = (const unsigned short*)(ws + OFF_SUT)
                               + (size_t)(b * O_ + og * 6) * D_ * R_;

    short8 pfrag = *(const short8*)(Pbf + (size_t)(nblk + rl) * R_ + lhi * 8);

    const float* __restrict__ Hrow = H + ((size_t)b * N_ + nblk + rl) * D_;
    f32x4 homa[4];
    #pragma unroll
    for (int db = 0; db < 4; ++db)
        homa[db] = oma * *(const f32x4*)(Hrow + db * 16 + lhi * 4);

    char* tb = (char*)tile;
    float* __restrict__ oblk = out + ((size_t)(b * O_ + og * 6) * N_ + nblk) * D_;

    short8 sf[2][4];
    #pragma unroll
    for (int db = 0; db < 4; ++db)
        sf[0][db] = *(const short8*)(SUT0 + (size_t)(db * 16 + l16) * R_ + lhi * 8);
    #pragma unroll
    for (int oi = 0; oi < 6; ++oi) {
        const int cur = oi & 1, nxt = cur ^ 1;
        // 1. issue NEXT o's SUT loads first (before this o's stores)
        if (oi < 5) {
            const unsigned short* Sn = SUT0 + (size_t)(oi + 1) * D_ * R_;
            #pragma unroll
            for (int db = 0; db < 4; ++db)
                sf[nxt][db] = *(const short8*)(Sn + (size_t)(db * 16 + l16) * R_ + lhi * 8);
        }
        // 2. MFMA + swizzled ds_write (wave-private rows)
        #pragma unroll
        for (int db = 0; db < 4; ++db) {
            f32x4 v = homa[db] + __builtin_amdgcn_mfma_f32_16x16x32_bf16(
                sf[cur][db], pfrag, (f32x4){0.f, 0.f, 0.f, 0.f}, 0, 0, 0);
            int c = (db * 64 + lhi * 16) ^ ((rl & 7) << 4);
            *(f32x4*)(tb + rl * 256 + c) = v;
        }
        // 3. wave-local linear read-back + full-line NON-TEMPORAL stores
        char* op = (char*)(oblk + (size_t)oi * N_ * D_);
        #pragma unroll
        for (int i = 0; i < 4; ++i) {
            int g = w * 4096 + i * 1024 + lane * 16;
            int rr = g >> 8;
            int cc = (g & 255) ^ ((rr & 7) << 4);
            f32x4 v = *(const f32x4*)(tb + rr * 256 + cc);
            __builtin_nontemporal_store(v, (f32x4*)(op + g));
        }
    }
}

extern "C" void kernel_launch(void* const* d_in, const int* in_sizes, int n_in,
                              void* d_out, int out_size, void* d_ws, size_t ws_size,
                              hipStream_t stream) {
    const float* H      = (const float*)d_in[0];
    const float* ts_out = (const float*)d_in[1];
    // d_in[2] is O (int scalar) — shapes are compile-time constants here
    const float* P_raw  = (const float*)d_in[3];
    const float* Q_raw  = (const float*)d_in[4];
    const float* W1     = (const float*)d_in[5];
    const float* b1     = (const float*)d_in[6];
    const float* W2     = (const float*)d_in[7];
    const float* b2     = (const float*)d_in[8];
    const float* alpha  = (const float*)d_in[9];
    float* out = (float*)d_out;
    float* ws  = (float*)d_ws;

    // 1. softplus(Q) -> Qsp
    k_softplus<<<dim3((N_ * R_ + 255) / 256), dim3(256), 0, stream>>>(Q_raw, ws);
    // 2a. partial U (1024 blocks, 8 waves/SIMD; +Pbf from b==0 blocks)
    k_upart<<<dim3(B_ * NCH_), dim3(512), 0, stream>>>(H, P_raw, ws);
    // 2b. reduce U + ctx (256 blocks)
    k_ured<<<dim3(B_, 8), dim3(256), 0, stream>>>(ws);
    // 3. MLP -> s -> SUT (bf16, [d][r])
    k_mlp<<<dim3(B_ * O_), dim3(128), 0, stream>>>(ts_out, W1, b1, W2, b2, alpha, ws);
    // 4. main fused output (nt full-line stores)
    k_main<<<dim3(2048), dim3(256), 0, stream>>>(H, alpha, ws, out);
}